// Round 1
// baseline (1144.472 us; speedup 1.0000x reference)
//
#include <hip/hip_runtime.h>
#include <math.h>

#define N_NODES 25000
#define E_EDGES 250000
#define HID 128
#define HEADS 8
#define HDIM 16
#define OUTC 64

__device__ __forceinline__ float gelu_f(float x) {
    return 0.5f * x * (1.0f + erff(x * 0.70710678118654752440f));
}

// ---------------- CSR build (edges sorted by destination) ----------------
__global__ void hist_kernel(const int* __restrict__ dst, int* __restrict__ cnt, int E) {
    int e = blockIdx.x * blockDim.x + threadIdx.x;
    if (e < E) atomicAdd(&cnt[dst[e]], 1);
}

// single block, 1024 threads; cnt becomes the scatter cursor (= exclusive prefix)
__global__ void scan_kernel(int* __restrict__ cnt, int* __restrict__ rowptr, int n) {
    __shared__ int buf[1024];
    int t = threadIdx.x;
    int per = (n + 1023) >> 10;
    int base = t * per;
    int s = 0;
    for (int i = 0; i < per; i++) { int idx = base + i; if (idx < n) s += cnt[idx]; }
    buf[t] = s;
    __syncthreads();
    for (int d = 1; d < 1024; d <<= 1) {
        int v = (t >= d) ? buf[t - d] : 0;
        __syncthreads();
        buf[t] += v;
        __syncthreads();
    }
    int off = (t == 0) ? 0 : buf[t - 1];
    for (int i = 0; i < per; i++) {
        int idx = base + i;
        if (idx < n) { int c = cnt[idx]; rowptr[idx] = off; cnt[idx] = off; off += c; }
    }
    if (t == 1023) rowptr[n] = buf[1023];
}

__global__ void scatter_kernel(const int* __restrict__ src, const int* __restrict__ dst,
                               int* __restrict__ cursor, int* __restrict__ srcs, int E) {
    int e = blockIdx.x * blockDim.x + threadIdx.x;
    if (e < E) {
        int p = atomicAdd(&cursor[dst[e]], 1);
        srcs[p] = src[e];
    }
}

// ---------------- dense matmul: C = epilogue(A[nrows,128] @ W[128,NOUT] + b) ----------------
// GELU_IN: apply exact gelu to A while staging. OUTMODE: 0 none, 1 relu, 2 gated residual.
template<int NOUT, int GELU_IN, int OUTMODE>
__global__ __launch_bounds__(256) void mm_kernel(
    const float* __restrict__ A, const float* __restrict__ W,
    const float* __restrict__ bias, const float* __restrict__ xres,
    const float* __restrict__ skipp, float* __restrict__ C, int nrows)
{
    constexpr int BM = 64;
    constexpr int CG = NOUT / 4;   // column groups of 4
    constexpr int RG = 256 / CG;   // row groups
    constexpr int TM = BM / RG;    // rows per thread
    __shared__ float sA[BM * HID];
    __shared__ float sW[HID * NOUT];
    int t = threadIdx.x;
    int row0 = blockIdx.x * BM;

    for (int i = t * 4; i < HID * NOUT; i += 1024)
        *(float4*)&sW[i] = *(const float4*)&W[i];
    for (int i = t * 4; i < BM * HID; i += 1024) {
        int r = i >> 7;
        float4 v = make_float4(0.f, 0.f, 0.f, 0.f);
        if (row0 + r < nrows) v = *(const float4*)&A[(size_t)(row0 + r) * HID + (i & 127)];
        if (GELU_IN) { v.x = gelu_f(v.x); v.y = gelu_f(v.y); v.z = gelu_f(v.z); v.w = gelu_f(v.w); }
        *(float4*)&sA[i] = v;
    }
    __syncthreads();

    int cg = t % CG, rg = t / CG;
    int j0 = cg * 4, r0 = rg * TM;
    float acc[TM][4];
    #pragma unroll
    for (int i = 0; i < TM; i++) { acc[i][0] = acc[i][1] = acc[i][2] = acc[i][3] = 0.f; }

    for (int k = 0; k < HID; k++) {
        float4 w = *(const float4*)&sW[k * NOUT + j0];
        #pragma unroll
        for (int i = 0; i < TM; i++) {
            float a = sA[(r0 + i) * HID + k];
            acc[i][0] = fmaf(a, w.x, acc[i][0]);
            acc[i][1] = fmaf(a, w.y, acc[i][1]);
            acc[i][2] = fmaf(a, w.z, acc[i][2]);
            acc[i][3] = fmaf(a, w.w, acc[i][3]);
        }
    }

    float beta = 0.f, omb = 0.f;
    if (OUTMODE == 2) { float sv = *skipp; beta = 1.f / (1.f + __expf(-sv)); omb = 1.f - beta; }
    #pragma unroll
    for (int i = 0; i < TM; i++) {
        int r = row0 + r0 + i;
        if (r >= nrows) continue;
        #pragma unroll
        for (int j = 0; j < 4; j++) {
            float v = acc[i][j] + bias[j0 + j];
            if (OUTMODE == 1) v = fmaxf(v, 0.f);
            if (OUTMODE == 2) v = beta * v + omb * xres[(size_t)r * HID + j0 + j];
            C[(size_t)r * NOUT + j0 + j] = v;
        }
    }
}

// ---------------- per-node head transform: ka = k @ a_rel[h], vm = v @ m_rel[h] ----------------
__global__ __launch_bounds__(256) void transform_kv(
    const float* __restrict__ kin, const float* __restrict__ vin,
    const float* __restrict__ Arel, const float* __restrict__ Mrel,
    float* __restrict__ ka, float* __restrict__ vm, int n)
{
    __shared__ float sA[HEADS * HDIM * HDIM];
    __shared__ float sM[HEADS * HDIM * HDIM];
    int t = threadIdx.x;
    for (int i = t; i < HEADS * HDIM * HDIM; i += 256) { sA[i] = Arel[i]; sM[i] = Mrel[i]; }
    __syncthreads();
    int lc = t & 127;          // channel
    int sub = t >> 7;          // which of 2 nodes this block-iter
    int h = lc >> 4, f = lc & 15;
    const float* Ah = &sA[h * 256];
    const float* Mh = &sM[h * 256];
    for (int node = blockIdx.x * 2 + sub; node < n; node += gridDim.x * 2) {
        const float* krow = &kin[(size_t)node * HID + h * 16];
        const float* vrow = &vin[(size_t)node * HID + h * 16];
        float acca = 0.f, accm = 0.f;
        #pragma unroll
        for (int d = 0; d < 16; d++) {
            float kd = krow[d], vd = vrow[d];
            acca = fmaf(kd, Ah[d * 16 + f], acca);
            accm = fmaf(vd, Mh[d * 16 + f], accm);
        }
        ka[(size_t)node * HID + lc] = acca;
        vm[(size_t)node * HID + lc] = accm;
    }
}

// ---------------- attention + aggregation: one wave per destination node ----------------
__global__ __launch_bounds__(256) void attn_kernel(
    const float* __restrict__ q, const float* __restrict__ ka, const float* __restrict__ vm,
    const int* __restrict__ rowptr, const int* __restrict__ srcs,
    const float* __restrict__ prel, float* __restrict__ agg, int n)
{
    int gid = blockIdx.x * blockDim.x + threadIdx.x;
    int nid = gid >> 6;
    int lane = gid & 63;
    if (nid >= n) return;
    int c0 = lane * 2;             // this lane owns channels c0, c0+1
    int h = c0 >> 4;               // lanes h*8..h*8+7 hold head h
    float2 qv = *(const float2*)&q[(size_t)nid * HID + c0];
    float p = prel[h] * 0.25f;     // p_rel[h] * 1/sqrt(D)
    float m = -INFINITY, ssum = 0.f;
    float ax = 0.f, ay = 0.f;
    int beg = rowptr[nid], end = rowptr[nid + 1];
    for (int i = beg; i < end; i++) {
        int s = srcs[i];
        float2 kv = *(const float2*)&ka[(size_t)s * HID + c0];
        float2 vv = *(const float2*)&vm[(size_t)s * HID + c0];
        float part = qv.x * kv.x + qv.y * kv.y;
        part += __shfl_xor(part, 1);
        part += __shfl_xor(part, 2);
        part += __shfl_xor(part, 4);   // sum over the 8 lanes of this head
        float score = part * p;
        float nm = fmaxf(m, score);
        float resc = __expf(m - nm);   // first iter: exp(-inf)=0 zeroes the empty state
        float e = __expf(score - nm);
        ssum = ssum * resc + e;
        ax = ax * resc + e * vv.x;
        ay = ay * resc + e * vv.y;
        m = nm;
    }
    float inv = 1.f / (ssum + 1e-16f);
    agg[(size_t)nid * HID + c0]     = ax * inv;
    agg[(size_t)nid * HID + c0 + 1] = ay * inv;
}

// ---------------- host orchestration ----------------
extern "C" void kernel_launch(void* const* d_in, const int* in_sizes, int n_in,
                              void* d_out, int out_size, void* d_ws, size_t ws_size,
                              hipStream_t stream)
{
    (void)in_sizes; (void)n_in; (void)out_size; (void)ws_size;
    const float* x_author = (const float*)d_in[0];
    const float* x_paper  = (const float*)d_in[1];
    const int*   e_writes = (const int*)d_in[2];
    const int*   e_rev    = (const int*)d_in[3];
    const float* W_in = (const float*)d_in[4];
    const float* b_in = (const float*)d_in[5];
    const float* Wq = (const float*)d_in[6];
    const float* bq = (const float*)d_in[7];
    const float* Wk = (const float*)d_in[8];
    const float* bk = (const float*)d_in[9];
    const float* Wv = (const float*)d_in[10];
    const float* bv = (const float*)d_in[11];
    const float* Wa = (const float*)d_in[12];
    const float* ba = (const float*)d_in[13];
    const float* skip = (const float*)d_in[14];
    const float* a_rel = (const float*)d_in[15];
    const float* m_rel = (const float*)d_in[16];
    const float* p_rel = (const float*)d_in[17];
    const float* W_out = (const float*)d_in[18];
    const float* b_out = (const float*)d_in[19];
    float* out = (float*)d_out;

    const size_t NB = (size_t)N_NODES * HID;
    float* F = (float*)d_ws;
    float* xP[2]  = { F + 0 * NB, F + 1 * NB };
    float* xQ[2]  = { F + 2 * NB, F + 3 * NB };
    float* qb     =   F + 4 * NB;
    float* kt     =   F + 5 * NB;
    float* vt     =   F + 6 * NB;
    float* ka     =   F + 7 * NB;
    float* vm     =   F + 8 * NB;
    float* agg[2] = { F + 9 * NB, F + 10 * NB };
    int* I = (int*)(F + 11 * NB);
    int* rowptr[2] = { I, I + (N_NODES + 1) };
    int* srcs[2]   = { I + 2 * (N_NODES + 1), I + 2 * (N_NODES + 1) + E_EDGES };
    int* cnt       =   I + 2 * (N_NODES + 1) + 2 * E_EDGES;

    dim3 blk(256);
    int mmGrid = (N_NODES + 63) / 64;
    int eGrid  = (E_EDGES + 255) / 256;
    int attnGrid = (N_NODES * 64 + 255) / 256;

    // CSR for both relations (relation 0: writes, author->paper; relation 1: rev)
    const int* eptr[2] = { e_writes, e_rev };
    for (int r = 0; r < 2; r++) {
        hipMemsetAsync(cnt, 0, N_NODES * sizeof(int), stream);
        hist_kernel<<<eGrid, blk, 0, stream>>>(eptr[r] + E_EDGES, cnt, E_EDGES);
        scan_kernel<<<1, 1024, 0, stream>>>(cnt, rowptr[r], N_NODES);
        scatter_kernel<<<eGrid, blk, 0, stream>>>(eptr[r], eptr[r] + E_EDGES, cnt, srcs[r], E_EDGES);
    }

    // input projection + relu
    mm_kernel<HID, 0, 1><<<mmGrid, blk, 0, stream>>>(x_author, W_in,             b_in,       nullptr, nullptr, xP[0], N_NODES);
    mm_kernel<HID, 0, 1><<<mmGrid, blk, 0, stream>>>(x_paper,  W_in + HID * HID, b_in + HID, nullptr, nullptr, xP[1], N_NODES);

    float* cur[2] = { xP[0], xP[1] };
    float* nxt[2] = { xQ[0], xQ[1] };
    const int rel_s[2] = { 0, 1 };
    const int rel_t[2] = { 1, 0 };

    for (int l = 0; l < 2; l++) {
        for (int r = 0; r < 2; r++) {
            int s = rel_s[r], tt = rel_t[r];
            size_t ws_ = (size_t)(l * 2 + s) * HID * HID;   // weight offset, source type
            size_t bs_ = (size_t)(l * 2 + s) * HID;
            size_t wt_ = (size_t)(l * 2 + tt) * HID * HID;  // weight offset, dest type
            size_t bt_ = (size_t)(l * 2 + tt) * HID;
            size_t ro  = (size_t)(l * 2 + r) * HEADS * HDIM * HDIM;
            mm_kernel<HID, 0, 0><<<mmGrid, blk, 0, stream>>>(cur[tt], Wq + wt_, bq + bt_, nullptr, nullptr, qb, N_NODES);
            mm_kernel<HID, 0, 0><<<mmGrid, blk, 0, stream>>>(cur[s],  Wk + ws_, bk + bs_, nullptr, nullptr, kt, N_NODES);
            mm_kernel<HID, 0, 0><<<mmGrid, blk, 0, stream>>>(cur[s],  Wv + ws_, bv + bs_, nullptr, nullptr, vt, N_NODES);
            transform_kv<<<2048, blk, 0, stream>>>(kt, vt, a_rel + ro, m_rel + ro, ka, vm, N_NODES);
            attn_kernel<<<attnGrid, blk, 0, stream>>>(qb, ka, vm, rowptr[r], srcs[r],
                                                      p_rel + (size_t)(l * 2 + r) * HEADS, agg[tt], N_NODES);
        }
        for (int tt = 0; tt < 2; tt++) {
            size_t wo = (size_t)(l * 2 + tt) * HID * HID;
            size_t bo = (size_t)(l * 2 + tt) * HID;
            mm_kernel<HID, 1, 2><<<mmGrid, blk, 0, stream>>>(agg[tt], Wa + wo, ba + bo, cur[tt],
                                                             skip + l * 2 + tt, nxt[tt], N_NODES);
        }
        float* t0 = cur[0]; float* t1 = cur[1];
        cur[0] = nxt[0]; cur[1] = nxt[1];
        nxt[0] = t0; nxt[1] = t1;
    }

    // final output projection
    mm_kernel<OUTC, 0, 0><<<mmGrid, blk, 0, stream>>>(cur[0], W_out, b_out, nullptr, nullptr, out, N_NODES);
    mm_kernel<OUTC, 0, 0><<<mmGrid, blk, 0, stream>>>(cur[1], W_out, b_out, nullptr, nullptr, out + (size_t)N_NODES * OUTC, N_NODES);
}

// Round 2
// 633.809 us; speedup vs baseline: 1.8057x; 1.8057x over previous
//
#include <hip/hip_runtime.h>
#include <math.h>

#define N_NODES 25000
#define E_EDGES 250000
#define HID 128
#define HEADS 8
#define HDIM 16
#define OUTC 64
#define NPB 98          // ceil(25000/256) blocks for node-space passes

__device__ __forceinline__ float gelu_f(float x) {
    return 0.5f * x * (1.0f + erff(x * 0.70710678118654752440f));
}

// ============================ CSR build ============================
__global__ void hist2(const int* __restrict__ e0, const int* __restrict__ e1,
                      int* __restrict__ cnt) {
    int r = blockIdx.y;
    const int* d = (r ? e1 : e0) + E_EDGES;   // dst row of edge_index
    int e = blockIdx.x * 256 + threadIdx.x;
    if (e < E_EDGES) atomicAdd(&cnt[r * N_NODES + d[e]], 1);
}

__global__ void csr_partial(const int* __restrict__ cnt, int* __restrict__ part) {
    int r = blockIdx.y, b = blockIdx.x, t = threadIdx.x;
    int idx = b * 256 + t;
    int v = (idx < N_NODES) ? cnt[r * N_NODES + idx] : 0;
    #pragma unroll
    for (int d = 1; d < 64; d <<= 1) v += __shfl_xor(v, d);
    __shared__ int ws[4];
    if ((t & 63) == 0) ws[t >> 6] = v;
    __syncthreads();
    if (t == 0) part[r * NPB + b] = ws[0] + ws[1] + ws[2] + ws[3];
}

// one block, 128 threads: wave w scans relation w's 98 partials -> exclusive
__global__ void csr_scanpart(int* __restrict__ part) {
    int w = threadIdx.x >> 6, lane = threadIdx.x & 63;
    int base = w * NPB;
    int a = part[base + lane];
    int b = (lane < NPB - 64) ? part[base + 64 + lane] : 0;
    int va = a, vb = b;
    #pragma unroll
    for (int d = 1; d < 64; d <<= 1) { int u = __shfl_up(va, d); if (lane >= d) va += u; }
    #pragma unroll
    for (int d = 1; d < 64; d <<= 1) { int u = __shfl_up(vb, d); if (lane >= d) vb += u; }
    int tot0 = __shfl(va, 63);
    part[base + lane] = va - a;                       // exclusive
    if (lane < NPB - 64) part[base + 64 + lane] = vb - b + tot0;
}

// block-level scan of 256 counts; writes rowptr and scatter cursor (reuses cnt)
__global__ void csr_write(int* __restrict__ cnt, const int* __restrict__ part,
                          int* __restrict__ rowptr) {
    int r = blockIdx.y, b = blockIdx.x, t = threadIdx.x;
    int idx = b * 256 + t;
    int v = (idx < N_NODES) ? cnt[r * N_NODES + idx] : 0;
    int lane = t & 63, w = t >> 6;
    int iv = v;
    #pragma unroll
    for (int d = 1; d < 64; d <<= 1) { int u = __shfl_up(iv, d); if (lane >= d) iv += u; }
    __shared__ int wtot[4];
    if (lane == 63) wtot[w] = iv;
    __syncthreads();
    int woff = part[r * NPB + b];
    #pragma unroll
    for (int i = 0; i < 4; i++) if (i < w) woff += wtot[i];
    int excl = woff + iv - v;
    if (idx < N_NODES) {
        rowptr[r * (N_NODES + 1) + idx] = excl;
        cnt[r * N_NODES + idx] = excl;                // becomes cursor
    }
    if (b == 0 && t == 0) rowptr[r * (N_NODES + 1) + N_NODES] = E_EDGES;
}

__global__ void scatter2(const int* __restrict__ e0, const int* __restrict__ e1,
                         int* __restrict__ cursor, int* __restrict__ srcs) {
    int r = blockIdx.y;
    const int* e = r ? e1 : e0;
    int i = blockIdx.x * 256 + threadIdx.x;
    if (i < E_EDGES) {
        int p = atomicAdd(&cursor[r * N_NODES + e[E_EDGES + i]], 1);
        srcs[r * E_EDGES + p] = e[i];
    }
}

// ================== fold a_rel/m_rel into QKV weights ==================
// Wf[p=(l*2+t)][128][384]: cols 0-127 Wq, 128-255 Wk@BD(a_rel[l,t]), 256-383 Wv@BD(m_rel[l,t])
__global__ __launch_bounds__(256) void fuse_weights(
    const float* __restrict__ Wq, const float* __restrict__ bq,
    const float* __restrict__ Wk, const float* __restrict__ bk,
    const float* __restrict__ Wv, const float* __restrict__ bv,
    const float* __restrict__ a_rel, const float* __restrict__ m_rel,
    float* __restrict__ Wf, float* __restrict__ bf)
{
    int p = blockIdx.x;                     // l*2+t  (relation index r == t)
    __shared__ float sA[2048], sM[2048];
    for (int i = threadIdx.x; i < 2048; i += 256) {
        sA[i] = a_rel[p * 2048 + i];
        sM[i] = m_rel[p * 2048 + i];
    }
    __syncthreads();
    const float* wq = Wq + (size_t)p * 16384;
    const float* wk = Wk + (size_t)p * 16384;
    const float* wv = Wv + (size_t)p * 16384;
    float* wf  = Wf + (size_t)p * 128 * 384;
    float* bfp = bf + p * 384;
    for (int idx = threadIdx.x; idx < 129 * 128; idx += 256) {
        int i = idx >> 7, c = idx & 127;
        int h = c >> 4, f = c & 15;
        const float* kr = (i < 128) ? &wk[i * 128 + h * 16] : &bk[p * 128 + h * 16];
        const float* vr = (i < 128) ? &wv[i * 128 + h * 16] : &bv[p * 128 + h * 16];
        float ak = 0.f, av = 0.f;
        #pragma unroll
        for (int d = 0; d < 16; d++) {
            ak = fmaf(kr[d], sA[h * 256 + d * 16 + f], ak);
            av = fmaf(vr[d], sM[h * 256 + d * 16 + f], av);
        }
        float qv = (i < 128) ? wq[i * 128 + c] : bq[p * 128 + c];
        if (i < 128) {
            wf[i * 384 + c] = qv;
            wf[i * 384 + 128 + c] = ak;
            wf[i * 384 + 256 + c] = av;
        } else {
            bfp[c] = qv; bfp[128 + c] = ak; bfp[256 + c] = av;
        }
    }
}

// ============================ dense matmul ============================
// C[z] = epilogue(A[z][nrows,128] @ W[z][128, wcols] + b[z]); col tile by blockIdx.y.
// GELU_IN: gelu on A while staging. OUTMODE: 0 none, 1 relu, 2 gated residual (in-place ok).
template<int BN, int TN, int GELU_IN, int OUTMODE>
__global__ __launch_bounds__(256) void mm2_kernel(
    const float* __restrict__ A0, const float* __restrict__ A1,
    const float* __restrict__ W0, const float* __restrict__ W1,
    const float* __restrict__ b0, const float* __restrict__ b1,
    const float* __restrict__ res0, const float* __restrict__ res1,
    const float* __restrict__ skipp,
    float* __restrict__ C0, float* __restrict__ C1,
    int nrows, int cstride)
{
    constexpr int BM = 128, BK = 64, PAD = 4;
    __shared__ float sAT[BK][BM + PAD];      // A transposed: [k][row]
    __shared__ float sW[BK][BN + PAD];       // W: [k][col]
    int z = blockIdx.z;
    const float* A    = z ? A1 : A0;
    const float* W    = z ? W1 : W0;
    const float* bias = z ? b1 : b0;
    const float* xres = z ? res1 : res0;
    float* C          = z ? C1 : C0;
    int t = threadIdx.x;
    int row0 = blockIdx.x * BM;
    int col0 = blockIdx.y * BN;
    int tx = t & 15, ty = t >> 4;
    int r0 = ty * 8, j0 = tx * TN;

    float acc[8][TN];
    #pragma unroll
    for (int i = 0; i < 8; i++)
        #pragma unroll
        for (int j = 0; j < TN; j++) acc[i][j] = 0.f;

    for (int k0 = 0; k0 < HID; k0 += BK) {
        // stage A tile (128x64), transposed into LDS
        #pragma unroll
        for (int ch = 0; ch < 8; ch++) {
            int i = (ch * 256 + t) * 4;
            int rr = i >> 6, c = i & 63;
            float4 v = make_float4(0.f, 0.f, 0.f, 0.f);
            int gr = row0 + rr;
            if (gr < nrows) v = *(const float4*)&A[(size_t)gr * HID + k0 + c];
            if (GELU_IN) { v.x = gelu_f(v.x); v.y = gelu_f(v.y); v.z = gelu_f(v.z); v.w = gelu_f(v.w); }
            sAT[c + 0][rr] = v.x; sAT[c + 1][rr] = v.y;
            sAT[c + 2][rr] = v.z; sAT[c + 3][rr] = v.w;
        }
        // stage W tile (64 x BN)
        constexpr int WCH = (BK * BN) / 1024;
        #pragma unroll
        for (int ch = 0; ch < WCH; ch++) {
            int i = (ch * 256 + t) * 4;
            int k = i / BN, c = i % BN;
            *(float4*)&sW[k][c] = *(const float4*)&W[(size_t)(k0 + k) * cstride + col0 + c];
        }
        __syncthreads();
        #pragma unroll 8
        for (int k = 0; k < BK; k++) {
            float4 a0 = *(float4*)&sAT[k][r0];
            float4 a1 = *(float4*)&sAT[k][r0 + 4];
            float av[8] = {a0.x, a0.y, a0.z, a0.w, a1.x, a1.y, a1.z, a1.w};
            float wv[TN];
            #pragma unroll
            for (int jj = 0; jj < TN / 4; jj++) {
                float4 w = *(float4*)&sW[k][j0 + jj * 4];
                wv[jj * 4 + 0] = w.x; wv[jj * 4 + 1] = w.y;
                wv[jj * 4 + 2] = w.z; wv[jj * 4 + 3] = w.w;
            }
            #pragma unroll
            for (int i = 0; i < 8; i++)
                #pragma unroll
                for (int j = 0; j < TN; j++)
                    acc[i][j] = fmaf(av[i], wv[j], acc[i][j]);
        }
        __syncthreads();
    }

    float beta = 0.f, omb = 0.f;
    if (OUTMODE == 2) { float sv = skipp[z]; beta = 1.f / (1.f + __expf(-sv)); omb = 1.f - beta; }
    #pragma unroll
    for (int i = 0; i < 8; i++) {
        int r = row0 + r0 + i;
        if (r >= nrows) continue;
        #pragma unroll
        for (int jj = 0; jj < TN / 4; jj++) {
            float4 v;
            float* vp = &v.x;
            #pragma unroll
            for (int j = 0; j < 4; j++) {
                float x = acc[i][jj * 4 + j] + bias[col0 + j0 + jj * 4 + j];
                if (OUTMODE == 1) x = fmaxf(x, 0.f);
                if (OUTMODE == 2) x = beta * x + omb * xres[(size_t)r * cstride + col0 + j0 + jj * 4 + j];
                vp[j] = x;
            }
            *(float4*)&C[(size_t)r * cstride + col0 + j0 + jj * 4] = v;
        }
    }
}

// ==================== attention: 32 lanes per dst node ====================
__global__ __launch_bounds__(256) void attn2_kernel(
    const float* __restrict__ qkv0, const float* __restrict__ qkv1,
    const int* __restrict__ rowptr, const int* __restrict__ srcs,
    const float* __restrict__ prel,          // p_rel + l*2*8
    float* __restrict__ agg0, float* __restrict__ agg1, int n)
{
    int r = blockIdx.y;                       // relation; src type = r, dst type = 1-r
    const float* qd = r ? qkv0 : qkv1;
    const float* sv = r ? qkv1 : qkv0;
    float* agg      = r ? agg0 : agg1;
    const int* rp = rowptr + r * (N_NODES + 1);
    const int* ss = srcs + r * E_EDGES;

    int gid = blockIdx.x * 256 + threadIdx.x;
    int nid = gid >> 5;
    int lane = gid & 31;
    if (nid >= n) return;
    int c0 = lane << 2;
    int h = lane >> 2;
    float4 qv = *(const float4*)&qd[(size_t)nid * 384 + c0];
    float p = prel[r * 8 + h] * 0.25f;        // p_rel * 1/sqrt(16)
    float m = -INFINITY, ssum = 0.f;
    float ax = 0.f, ay = 0.f, az = 0.f, aw = 0.f;
    int beg = rp[nid], end = rp[nid + 1];
    for (int i = beg; i < end; i++) {
        int s = ss[i];
        const float* srow = &sv[(size_t)s * 384];
        float4 kv = *(const float4*)&srow[128 + c0];
        float4 vv = *(const float4*)&srow[256 + c0];
        float part = qv.x * kv.x + qv.y * kv.y + qv.z * kv.z + qv.w * kv.w;
        part += __shfl_xor(part, 1);
        part += __shfl_xor(part, 2);
        float score = part * p;
        float nm = fmaxf(m, score);
        float resc = __expf(m - nm);          // first iter: exp(-inf)=0
        float e = __expf(score - nm);
        ssum = ssum * resc + e;
        ax = ax * resc + e * vv.x;
        ay = ay * resc + e * vv.y;
        az = az * resc + e * vv.z;
        aw = aw * resc + e * vv.w;
        m = nm;
    }
    float inv = 1.f / (ssum + 1e-16f);
    float4 o = make_float4(ax * inv, ay * inv, az * inv, aw * inv);
    *(float4*)&agg[(size_t)nid * HID + c0] = o;
}

// ============================ orchestration ============================
extern "C" void kernel_launch(void* const* d_in, const int* in_sizes, int n_in,
                              void* d_out, int out_size, void* d_ws, size_t ws_size,
                              hipStream_t stream)
{
    (void)in_sizes; (void)n_in; (void)out_size; (void)ws_size;
    const float* x_author = (const float*)d_in[0];
    const float* x_paper  = (const float*)d_in[1];
    const int*   e_writes = (const int*)d_in[2];
    const int*   e_rev    = (const int*)d_in[3];
    const float* W_in = (const float*)d_in[4];
    const float* b_in = (const float*)d_in[5];
    const float* Wq = (const float*)d_in[6];
    const float* bq = (const float*)d_in[7];
    const float* Wk = (const float*)d_in[8];
    const float* bk = (const float*)d_in[9];
    const float* Wv = (const float*)d_in[10];
    const float* bv = (const float*)d_in[11];
    const float* Wa = (const float*)d_in[12];
    const float* ba = (const float*)d_in[13];
    const float* skip = (const float*)d_in[14];
    const float* a_rel = (const float*)d_in[15];
    const float* m_rel = (const float*)d_in[16];
    const float* p_rel = (const float*)d_in[17];
    const float* W_out = (const float*)d_in[18];
    const float* b_out = (const float*)d_in[19];
    float* out = (float*)d_out;

    const size_t NB = (size_t)N_NODES * HID;
    float* F = (float*)d_ws;
    float* cur0 = F;            float* cur1 = F + NB;
    float* agg0 = F + 2 * NB;   float* agg1 = F + 3 * NB;
    float* qkv0 = F + 4 * NB;   float* qkv1 = F + 7 * NB;   // [N][384] each
    float* Wf   = F + 10 * NB;                               // 4*128*384
    float* bf   = Wf + 4 * 128 * 384;                        // 4*384
    int* I      = (int*)(bf + 4 * 384);
    int* cnt    = I;                                         // 2*N (becomes cursor)
    int* part   = I + 2 * N_NODES;                           // 2*NPB
    int* rowptr = part + 2 * NPB;                            // 2*(N+1)
    int* srcs   = rowptr + 2 * (N_NODES + 1);                // 2*E

    dim3 blk(256);
    int eGrid = (E_EDGES + 255) / 256;
    int mmX = (N_NODES + 127) / 128;                         // 196
    int attnX = (N_NODES * 32 + 255) / 256;                  // 3125

    // ---- CSR for both relations in parallel grids ----
    hipMemsetAsync(cnt, 0, 2 * N_NODES * sizeof(int), stream);
    hist2<<<dim3(eGrid, 2), blk, 0, stream>>>(e_writes, e_rev, cnt);
    csr_partial<<<dim3(NPB, 2), blk, 0, stream>>>(cnt, part);
    csr_scanpart<<<1, 128, 0, stream>>>(part);
    csr_write<<<dim3(NPB, 2), blk, 0, stream>>>(cnt, part, rowptr);
    scatter2<<<dim3(eGrid, 2), blk, 0, stream>>>(e_writes, e_rev, cnt, srcs);

    // ---- fold a_rel/m_rel into QKV weights ----
    fuse_weights<<<4, 256, 0, stream>>>(Wq, bq, Wk, bk, Wv, bv, a_rel, m_rel, Wf, bf);

    // ---- input projection + relu ----
    mm2_kernel<128, 8, 0, 1><<<dim3(mmX, 1, 2), blk, 0, stream>>>(
        x_author, x_paper, W_in, W_in + 16384, b_in, b_in + HID,
        nullptr, nullptr, nullptr, cur0, cur1, N_NODES, HID);

    for (int l = 0; l < 2; l++) {
        // fused QKV' per type: [N,128] @ [128,384]
        mm2_kernel<128, 8, 0, 0><<<dim3(mmX, 3, 2), blk, 0, stream>>>(
            cur0, cur1,
            Wf + (size_t)(l * 2 + 0) * 128 * 384, Wf + (size_t)(l * 2 + 1) * 128 * 384,
            bf + (l * 2 + 0) * 384, bf + (l * 2 + 1) * 384,
            nullptr, nullptr, nullptr, qkv0, qkv1, N_NODES, 384);
        // both relations' attention in one dispatch
        attn2_kernel<<<dim3(attnX, 2), blk, 0, stream>>>(
            qkv0, qkv1, rowptr, srcs, p_rel + (size_t)l * 16, agg0, agg1, N_NODES);
        // out-proj: gelu(agg)@Wa + ba, gated residual, in-place into cur
        mm2_kernel<128, 8, 1, 2><<<dim3(mmX, 1, 2), blk, 0, stream>>>(
            agg0, agg1,
            Wa + (size_t)(l * 2 + 0) * 16384, Wa + (size_t)(l * 2 + 1) * 16384,
            ba + (l * 2 + 0) * HID, ba + (l * 2 + 1) * HID,
            cur0, cur1, skip + l * 2, cur0, cur1, N_NODES, HID);
    }

    // ---- final projection [N,128]@[128,64] for both types ----
    mm2_kernel<64, 4, 0, 0><<<dim3(mmX, 1, 2), blk, 0, stream>>>(
        cur0, cur1, W_out, W_out, b_out, b_out,
        nullptr, nullptr, nullptr, out, out + (size_t)N_NODES * OUTC, N_NODES, OUTC);
}